// Round 1
// baseline (90.261 us; speedup 1.0000x reference)
//
#include <hip/hip_runtime.h>

// IDWT3D (Haar, stride-2 transposed conv, groups=C):
// out[b,c,2d+i,2h+j,2w+k] = sum_s y[b,c,s,d,h,w] * K[s,i,j,k]
// y = concat(low, highs) over s (s=0 -> low, s=1..7 -> highs).
//
// Shapes (fixed by the problem):
//   low   [2,32,48,48,48] f32
//   highs [2,32,7,48,48,48] f32
//   K     [8,2,2,2] f32
//   out   [2,32,96,96,96] f32
//
// Memory-bound: ~227 MB read + ~227 MB write -> ~72 us floor @ 6.3 TB/s.

constexpr int Bn = 2, Cn = 32, Dn = 48, Hn = 48, Wn = 48;
constexpr int WPT = 4;               // coarse w voxels per thread (float4 loads)
constexpr int WQ  = Wn / WPT;        // 12
constexpr int NT  = Bn * Cn * Dn * Hn * WQ;  // 1,769,472 threads total
constexpr int SUBBAND_STRIDE = Dn * Hn * Wn; // 110,592

__global__ __launch_bounds__(256) void idwt3d_kernel(
    const float* __restrict__ low,
    const float* __restrict__ highs,
    const float* __restrict__ ker,
    float* __restrict__ out)
{
    __shared__ float sk[64];
    if (threadIdx.x < 64) sk[threadIdx.x] = ker[threadIdx.x];
    __syncthreads();

    int idx = blockIdx.x * 256 + threadIdx.x;
    if (idx >= NT) return;

    int wq = idx % WQ;
    int t  = idx / WQ;
    int h  = t % Hn; t /= Hn;
    int d  = t % Dn; t /= Dn;
    int bc = t;                      // b*C + c  (0..63)
    int w0 = wq * WPT;

    // ---- load 8 subband values for 4 consecutive w (all float4, coalesced) ----
    float y[8][4];
    {
        int cvox = ((bc * Dn + d) * Hn + h) * Wn + w0;
        float4 v = *reinterpret_cast<const float4*>(low + cvox);
        y[0][0] = v.x; y[0][1] = v.y; y[0][2] = v.z; y[0][3] = v.w;

        int hbase = ((bc * 7 * Dn + d) * Hn + h) * Wn + w0;
#pragma unroll
        for (int s = 0; s < 7; ++s) {
            float4 u = *reinterpret_cast<const float4*>(highs + hbase + s * SUBBAND_STRIDE);
            y[s + 1][0] = u.x; y[s + 1][1] = u.y; y[s + 1][2] = u.z; y[s + 1][3] = u.w;
        }
    }

    // ---- compute + store: 4 output rows (i,j), each 8 contiguous floats ----
    const int D2 = 2 * Dn, H2 = 2 * Hn, W2 = 2 * Wn;
    const int od = 2 * d, oh = 2 * h, ow = 2 * w0;

#pragma unroll
    for (int i = 0; i < 2; ++i) {
#pragma unroll
        for (int j = 0; j < 2; ++j) {
            // hoist the 16 tap weights for this (i,j) into registers
            float k0[8], k1[8];
#pragma unroll
            for (int s = 0; s < 8; ++s) {
                k0[s] = sk[s * 8 + i * 4 + j * 2 + 0];
                k1[s] = sk[s * 8 + i * 4 + j * 2 + 1];
            }

            float o[8];
#pragma unroll
            for (int wsub = 0; wsub < 4; ++wsub) {
                float a0 = 0.f, a1 = 0.f;
#pragma unroll
                for (int s = 0; s < 8; ++s) {
                    a0 = fmaf(y[s][wsub], k0[s], a0);
                    a1 = fmaf(y[s][wsub], k1[s], a1);
                }
                o[2 * wsub + 0] = a0;
                o[2 * wsub + 1] = a1;
            }

            int obase = ((bc * D2 + (od + i)) * H2 + (oh + j)) * W2 + ow;
            *reinterpret_cast<float4*>(out + obase + 0) = make_float4(o[0], o[1], o[2], o[3]);
            *reinterpret_cast<float4*>(out + obase + 4) = make_float4(o[4], o[5], o[6], o[7]);
        }
    }
}

extern "C" void kernel_launch(void* const* d_in, const int* in_sizes, int n_in,
                              void* d_out, int out_size, void* d_ws, size_t ws_size,
                              hipStream_t stream) {
    const float* low   = (const float*)d_in[0];
    const float* highs = (const float*)d_in[1];
    const float* ker   = (const float*)d_in[2];
    float* out = (float*)d_out;

    constexpr int BLK = 256;
    constexpr int GRID = NT / BLK;   // 6912, exact cover
    idwt3d_kernel<<<GRID, BLK, 0, stream>>>(low, highs, ker, out);
}

// Round 3
// 68.701 us; speedup vs baseline: 1.3138x; 1.3138x over previous
//
#include <hip/hip_runtime.h>

// IDWT3D (Haar, stride-2 transposed conv, groups=C):
// out[b,c,2d+i,2h+j,2w+k] = sum_s y[b,c,s,d,h,w] * K[s,i,j,k]
// y = concat(low, highs) over s (s=0 -> low, s=1..7 -> highs).
//
// Shapes: low [2,32,48,48,48] f32, highs [2,32,7,48,48,48] f32,
//         K [8,2,2,2] f32, out [2,32,96,96,96] f32.
//
// Memory-bound: ~227 MB read + ~227 MB write -> ~72 us floor @ 6.3 TB/s copy ceiling.
//
// R3: same as R2 but with clang ext_vector types (HIP's float4 class is not
// accepted by __builtin_nontemporal_store). WPT=2: every store instruction is
// fully dense across the wave (one 16B vector per output row per thread),
// loads are dense float2 (8 B/lane). Nontemporal stores (streaming output).

typedef float f32x4 __attribute__((ext_vector_type(4)));
typedef float f32x2 __attribute__((ext_vector_type(2)));

constexpr int Bn = 2, Cn = 32, Dn = 48, Hn = 48, Wn = 48;
constexpr int WPT = 2;               // coarse w voxels per thread
constexpr int WQ  = Wn / WPT;        // 24
constexpr int NT  = Bn * Cn * Dn * Hn * WQ;  // 3,538,944 threads
constexpr int SUBBAND_STRIDE = Dn * Hn * Wn; // 110,592

__global__ __launch_bounds__(256) void idwt3d_kernel(
    const float* __restrict__ low,
    const float* __restrict__ highs,
    const float* __restrict__ ker,
    float* __restrict__ out)
{
    __shared__ float sk[64];
    if (threadIdx.x < 64) sk[threadIdx.x] = ker[threadIdx.x];
    __syncthreads();

    int idx = blockIdx.x * 256 + threadIdx.x;
    if (idx >= NT) return;

    int wq = idx % WQ;
    int t  = idx / WQ;
    int h  = t % Hn; t /= Hn;
    int d  = t % Dn; t /= Dn;
    int bc = t;                      // b*C + c  (0..63)
    int w0 = wq * WPT;

    // ---- load 8 subband values for 2 consecutive w (dense float2 loads) ----
    float y[8][2];
    {
        int cvox = ((bc * Dn + d) * Hn + h) * Wn + w0;
        f32x2 v = *reinterpret_cast<const f32x2*>(low + cvox);
        y[0][0] = v.x; y[0][1] = v.y;

        int hbase = ((bc * 7 * Dn + d) * Hn + h) * Wn + w0;
#pragma unroll
        for (int s = 0; s < 7; ++s) {
            f32x2 u = *reinterpret_cast<const f32x2*>(highs + hbase + s * SUBBAND_STRIDE);
            y[s + 1][0] = u.x; y[s + 1][1] = u.y;
        }
    }

    // ---- compute + store: 4 output rows (i,j), one dense 16B store each ----
    const int D2 = 2 * Dn, H2 = 2 * Hn, W2 = 2 * Wn;
    const int od = 2 * d, oh = 2 * h, ow = 2 * w0;

#pragma unroll
    for (int i = 0; i < 2; ++i) {
#pragma unroll
        for (int j = 0; j < 2; ++j) {
            float k0[8], k1[8];
#pragma unroll
            for (int s = 0; s < 8; ++s) {
                k0[s] = sk[s * 8 + i * 4 + j * 2 + 0];
                k1[s] = sk[s * 8 + i * 4 + j * 2 + 1];
            }

            f32x4 o;
#pragma unroll
            for (int wsub = 0; wsub < 2; ++wsub) {
                float a0 = 0.f, a1 = 0.f;
#pragma unroll
                for (int s = 0; s < 8; ++s) {
                    a0 = fmaf(y[s][wsub], k0[s], a0);
                    a1 = fmaf(y[s][wsub], k1[s], a1);
                }
                o[2 * wsub + 0] = a0;
                o[2 * wsub + 1] = a1;
            }

            int obase = ((bc * D2 + (od + i)) * H2 + (oh + j)) * W2 + ow;
            __builtin_nontemporal_store(o, reinterpret_cast<f32x4*>(out + obase));
        }
    }
}

extern "C" void kernel_launch(void* const* d_in, const int* in_sizes, int n_in,
                              void* d_out, int out_size, void* d_ws, size_t ws_size,
                              hipStream_t stream) {
    const float* low   = (const float*)d_in[0];
    const float* highs = (const float*)d_in[1];
    const float* ker   = (const float*)d_in[2];
    float* out = (float*)d_out;

    constexpr int BLK = 256;
    constexpr int GRID = NT / BLK;   // 13824, exact cover
    idwt3d_kernel<<<GRID, BLK, 0, stream>>>(low, highs, ker, out);
}